// Round 16
// baseline (37.067 us; speedup 1.0000x reference)
//
#include <hip/hip_runtime.h>

#define POOL 7
#define CCH 256
#define HH 100
#define WW 100
#define HW (HH * WW)
#define MAXTH 28          // worst-case row span (<=27)
#define NTAP 14           // POOL * NSAMP samples per axis
#define NT 256            // 4 waves per block
#define ITEMS 8           // channels per wave (2-slot depth-2 pipeline)
#define SLOTF 896         // floats per LDS slot = MAXTH*8blocks*4 (3584 B)

static constexpr float SCALE = 0.125f;

// lo/hi/w1/w2 for sample k (0..13) along one axis (reference semantics).
__device__ __forceinline__ void tap_calc(float s0, float step, int k, int L,
                                         int& lo, int& hi, float& w1, float& w2)
{
    const int   p  = k >> 1, si = k & 1;
    const float g  = (float)p + ((float)si + 0.5f) * 0.5f;
    const float c  = s0 + g * step;
    const float Lf = (float)L;
    const bool  valid = (c > -1.0f) && (c < Lf);
    float cl = fminf(fmaxf(c, 0.0f), Lf - 1.0f);
    lo = (int)floorf(cl);
    if (lo > L - 1) lo = L - 1;
    hi = lo + 1;
    if (hi > L - 1) hi = L - 1;
    const float fr = cl - (float)lo;
    w1 = valid ? 1.0f - fr : 0.0f;
    w2 = valid ? fr : 0.0f;
}

// Per-wave pipeline over 8 channels of one ROI; 2 slots, depth-2 (R14's
// proven sync pattern): {wait vmcnt(NJ), compute k, lgkmcnt(0)+sched_barrier,
// reissue k+2 into the freed slot}. Stores deferred past the final vmcnt(0)
// (stores share vmcnt with loads).
template <int NJ>
__device__ __forceinline__ void run8(
    const float* __restrict__ x, float* __restrict__ out,
    float* slot, int n, int c0, int r, int xmin_al, int ymin,
    int tot, int magic, int nb4, int lane,
    const int* off, const float* wgt, int bin)
{
    const float* xa = x + ((size_t)(n * CCH + c0)) * HW
                        + (size_t)ymin * WW + xmin_al;

    int go[NJ]; bool act[NJ];
    #pragma unroll
    for (int j = 0; j < NJ; ++j) {
        const int idx = lane + 64 * j;
        const int row = (idx * magic) >> 16;
        const int b   = idx - row * nb4;
        go[j]  = row * WW + (b << 2);
        act[j] = (j < NJ - 1) || (idx < tot);
    }

    float* const sA = slot;
    float* const sB = slot + SLOTF;

#define ISSUE(k, dst)                                                        \
    _Pragma("unroll")                                                        \
    for (int j = 0; j < NJ; ++j)                                             \
        if (act[j])                                                          \
            __builtin_amdgcn_global_load_lds(                                \
                (const __attribute__((address_space(1))) void*)(xa + (size_t)(k) * HW + go[j]), \
                (__attribute__((address_space(3))) void*)((dst) + j * 256),  \
                16, 0, 0);

#define COMPUTE(dst, buf)                                                    \
    {                                                                        \
        float a0 = 0.f, a1 = 0.f, a2 = 0.f, a3 = 0.f;                        \
        _Pragma("unroll")                                                    \
        for (int p = 0; p < 8; p += 4) {                                     \
            a0 += wgt[2*p+0] * (buf)[off[p+0]] + wgt[2*p+1] * (buf)[off[p+0]+1]; \
            a1 += wgt[2*p+2] * (buf)[off[p+1]] + wgt[2*p+3] * (buf)[off[p+1]+1]; \
            a2 += wgt[2*p+4] * (buf)[off[p+2]] + wgt[2*p+5] * (buf)[off[p+2]+1]; \
            a3 += wgt[2*p+6] * (buf)[off[p+3]] + wgt[2*p+7] * (buf)[off[p+3]+1]; \
        }                                                                    \
        dst = (a0 + a1) + (a2 + a3);                                         \
    }

#define WAITN(N)  asm volatile("s_waitcnt vmcnt(%0)" :: "n"(N) : "memory")
#define LGDRAIN() do { asm volatile("s_waitcnt lgkmcnt(0)" ::: "memory");    \
                       __builtin_amdgcn_sched_barrier(0); } while (0)

    ISSUE(0, sA)
    ISSUE(1, sB)

    float acc0, acc1, acc2, acc3, acc4, acc5, acc6, acc7;

    WAITN(NJ); COMPUTE(acc0, sA) LGDRAIN(); ISSUE(2, sA)
    WAITN(NJ); COMPUTE(acc1, sB) LGDRAIN(); ISSUE(3, sB)
    WAITN(NJ); COMPUTE(acc2, sA) LGDRAIN(); ISSUE(4, sA)
    WAITN(NJ); COMPUTE(acc3, sB) LGDRAIN(); ISSUE(5, sB)
    WAITN(NJ); COMPUTE(acc4, sA) LGDRAIN(); ISSUE(6, sA)
    WAITN(NJ); COMPUTE(acc5, sB) LGDRAIN(); ISSUE(7, sB)
    WAITN(NJ); COMPUTE(acc6, sA)
    WAITN(0);  COMPUTE(acc7, sB)

#undef ISSUE
#undef COMPUTE
#undef WAITN
#undef LGDRAIN

    if (lane < POOL * POOL) {
        float* ob = out + ((size_t)(r * CCH + c0)) * (POOL * POOL) + bin;
        ob[0 * POOL * POOL] = acc0 * 0.25f;
        ob[1 * POOL * POOL] = acc1 * 0.25f;
        ob[2 * POOL * POOL] = acc2 * 0.25f;
        ob[3 * POOL * POOL] = acc3 * 0.25f;
        ob[4 * POOL * POOL] = acc4 * 0.25f;
        ob[5 * POOL * POOL] = acc5 * 0.25f;
        ob[6 * POOL * POOL] = acc6 * 0.25f;
        ob[7 * POOL * POOL] = acc7 * 0.25f;
    }
}

// Single fused kernel: one block = 4 waves x 8 channels = 32 ch of one ROI.
__global__ __launch_bounds__(NT) void roi_main(
    const float* __restrict__ x, const float* __restrict__ rois,
    float* __restrict__ out)
{
    __shared__ float tile[(NT / 64) * 2 * SLOTF];   // 28672 B

    const int bid  = blockIdx.x;
    const int r    = bid >> 3;                 // 8 groups per ROI
    const int g    = bid & 7;
    const int wid  = threadIdx.x >> 6;
    const int lane = threadIdx.x & 63;
    const int c0   = g * (ITEMS * NT / 64) + wid * ITEMS;

    // ---- per-ROI params (L2-hot broadcast reads) ----
    const float r0  = rois[r * 5 + 0];
    const float sx0 = rois[r * 5 + 1] * SCALE - 0.5f;
    const float sy0 = rois[r * 5 + 2] * SCALE - 0.5f;
    const float bw  = (rois[r * 5 + 3] * SCALE - 0.5f - sx0) * (1.0f / POOL);
    const float bh  = (rois[r * 5 + 4] * SCALE - 0.5f - sy0) * (1.0f / POOL);
    const int   n   = (int)r0;

    // ---- this lane's raw taps (x pair folded for pair-reads, y standard) --
    const int bin = (lane < POOL * POOL) ? lane : POOL * POOL - 1;
    const int py  = bin / POOL;
    const int px  = bin - py * POOL;

    int xlo0r, xlo1r; float wx10, wx20, wx11, wx21;
    {
        int lo, hi; float w1, w2;
        tap_calc(sx0, bw, px * 2,     WW, lo, hi, w1, w2);
        if (hi == lo) { w1 += w2; w2 = 0.0f; }
        xlo0r = lo; wx10 = w1; wx20 = w2;
        tap_calc(sx0, bw, px * 2 + 1, WW, lo, hi, w1, w2);
        if (hi == lo) { w1 += w2; w2 = 0.0f; }
        xlo1r = lo; wx11 = w1; wx21 = w2;
    }
    int ylo0r, yhi0r, ylo1r, yhi1r; float wy10, wy20, wy11, wy21;
    tap_calc(sy0, bh, py * 2,     HH, ylo0r, yhi0r, wy10, wy20);
    tap_calc(sy0, bh, py * 2 + 1, HH, ylo1r, yhi1r, wy11, wy21);

    // ---- bbox via readlane (taps monotonic: lane 0 = min, lane 48 = max) --
    const int xmin_al = __builtin_amdgcn_readlane(xlo0r, 0) & ~3;
    const int ymin    = __builtin_amdgcn_readlane(ylo0r, 0);
    const int xmaxr   = __builtin_amdgcn_readlane(xlo1r, 48);
    const int ymaxr   = __builtin_amdgcn_readlane(yhi1r, 48);
    int TH  = ymaxr - ymin + 1;             if (TH > MAXTH) TH = MAXTH;
    int nb4 = ((min(xmaxr + 1, WW - 1) - xmin_al) >> 2) + 1;
    if (nb4 > 8) nb4 = 8;
    const int magic = (int)ceilf(65536.0f / (float)nb4);
    const int tot   = TH * nb4;
    const int TWp   = nb4 << 2;
    const int nj    = (tot + 63) >> 6;      // 1..4

    // ---- 8 pair-bases + 16 weights (shared by all 8 channels) ----
    int   off[8];
    float wgt[16];
    {
        const int xlo0 = max(xlo0r - xmin_al, 0);
        const int xlo1 = max(xlo1r - xmin_al, 0);
        const int rl0  = max(ylo0r - ymin, 0) * TWp;
        const int rh0  = max(yhi0r - ymin, 0) * TWp;
        const int rl1  = max(ylo1r - ymin, 0) * TWp;
        const int rh1  = max(yhi1r - ymin, 0) * TWp;
        off[0] = rl0 + xlo0;  wgt[0]  = wy10 * wx10;  wgt[1]  = wy10 * wx20;
        off[1] = rl0 + xlo1;  wgt[2]  = wy10 * wx11;  wgt[3]  = wy10 * wx21;
        off[2] = rh0 + xlo0;  wgt[4]  = wy20 * wx10;  wgt[5]  = wy20 * wx20;
        off[3] = rh0 + xlo1;  wgt[6]  = wy20 * wx11;  wgt[7]  = wy20 * wx21;
        off[4] = rl1 + xlo0;  wgt[8]  = wy11 * wx10;  wgt[9]  = wy11 * wx20;
        off[5] = rl1 + xlo1;  wgt[10] = wy11 * wx11;  wgt[11] = wy11 * wx21;
        off[6] = rh1 + xlo0;  wgt[12] = wy21 * wx10;  wgt[13] = wy21 * wx20;
        off[7] = rh1 + xlo1;  wgt[14] = wy21 * wx11;  wgt[15] = wy21 * wx21;
    }

    float* slot = tile + wid * (2 * SLOTF);

    switch (nj) {
    case 1:  run8<1>(x, out, slot, n, c0, r, xmin_al, ymin, tot, magic, nb4, lane, off, wgt, bin); break;
    case 2:  run8<2>(x, out, slot, n, c0, r, xmin_al, ymin, tot, magic, nb4, lane, off, wgt, bin); break;
    case 3:  run8<3>(x, out, slot, n, c0, r, xmin_al, ymin, tot, magic, nb4, lane, off, wgt, bin); break;
    default: run8<4>(x, out, slot, n, c0, r, xmin_al, ymin, tot, magic, nb4, lane, off, wgt, bin); break;
    }
}

extern "C" void kernel_launch(void* const* d_in, const int* in_sizes, int n_in,
                              void* d_out, int out_size, void* d_ws, size_t ws_size,
                              hipStream_t stream) {
    const float* x    = (const float*)d_in[0];
    const float* rois = (const float*)d_in[1];
    float*       out  = (float*)d_out;

    const int R = in_sizes[1] / 5;
    roi_main<<<R * 8, NT, 0, stream>>>(x, rois, out);
}

// Round 17
// 34.769 us; speedup vs baseline: 1.0661x; 1.0661x over previous
//
#include <hip/hip_runtime.h>

#define POOL 7
#define CCH 256
#define HH 100
#define WW 100
#define HW (HH * WW)
#define MAXTH 28          // worst-case row span (<=27)
#define NTAP 14           // POOL * NSAMP samples per axis
#define NT 256            // 4 waves per block
#define ITEMS 4           // channels per wave (2-slot double buffer)
#define SLOTF 896         // floats per LDS slot = MAXTH*8blocks*4 (3584 B)

static constexpr float SCALE = 0.125f;

// lo/hi/w1/w2 for sample k (0..13) along one axis (reference semantics).
__device__ __forceinline__ void tap_calc(float s0, float step, int k, int L,
                                         int& lo, int& hi, float& w1, float& w2)
{
    const int   p  = k >> 1, si = k & 1;
    const float g  = (float)p + ((float)si + 0.5f) * 0.5f;
    const float c  = s0 + g * step;
    const float Lf = (float)L;
    const bool  valid = (c > -1.0f) && (c < Lf);
    float cl = fminf(fmaxf(c, 0.0f), Lf - 1.0f);
    lo = (int)floorf(cl);
    if (lo > L - 1) lo = L - 1;
    hi = lo + 1;
    if (hi > L - 1) hi = L - 1;
    const float fr = cl - (float)lo;
    w1 = valid ? 1.0f - fr : 0.0f;
    w2 = valid ? fr : 0.0f;
}

// Per-wave pipeline over 4 channels of one ROI. DMA ch0->A, ch1->B; then
// {wait NJ, compute k, reissue k+2 into freed slot}; stores deferred past
// the final vmcnt(0) (stores share vmcnt with loads).
template <int NJ>
__device__ __forceinline__ void run4(
    const float* __restrict__ x, float* __restrict__ out,
    float* slot, int n, int c0, int r, int xmin_al, int ymin,
    int TWp, int tot, int magic, int nb4, int lane,
    const int* off, const float* wgt, int bin)
{
    const float* xc[ITEMS];
    {
        const float* xa = x + ((size_t)(n * CCH + c0)) * HW
                            + (size_t)ymin * WW + xmin_al;
        #pragma unroll
        for (int k = 0; k < ITEMS; ++k) xc[k] = xa + (size_t)k * HW;
    }
    float* slotB = slot + SLOTF;

    int go[NJ]; bool act[NJ];
    #pragma unroll
    for (int j = 0; j < NJ; ++j) {
        const int idx = lane + 64 * j;
        const int row = (idx * magic) >> 16;
        const int b   = idx - row * nb4;
        go[j]  = row * WW + (b << 2);
        act[j] = (j < NJ - 1) || (idx < tot);
    }

#define ISSUE(k, dst)                                                        \
    _Pragma("unroll")                                                        \
    for (int j = 0; j < NJ; ++j)                                             \
        if (act[j])                                                          \
            __builtin_amdgcn_global_load_lds(                                \
                (const __attribute__((address_space(1))) void*)(xc[k] + go[j]), \
                (__attribute__((address_space(3))) void*)((dst) + j * 256),  \
                16, 0, 0);

#define COMPUTE(dst, buf)                                                    \
    {                                                                        \
        float a0 = 0.f, a1 = 0.f, a2 = 0.f, a3 = 0.f;                        \
        _Pragma("unroll")                                                    \
        for (int p = 0; p < 8; p += 4) {                                     \
            a0 += wgt[2*p+0] * (buf)[off[p+0]] + wgt[2*p+1] * (buf)[off[p+0]+1]; \
            a1 += wgt[2*p+2] * (buf)[off[p+1]] + wgt[2*p+3] * (buf)[off[p+1]+1]; \
            a2 += wgt[2*p+4] * (buf)[off[p+2]] + wgt[2*p+5] * (buf)[off[p+2]+1]; \
            a3 += wgt[2*p+6] * (buf)[off[p+3]] + wgt[2*p+7] * (buf)[off[p+3]+1]; \
        }                                                                    \
        dst = (a0 + a1) + (a2 + a3);                                         \
    }

    ISSUE(0, slot)
    ISSUE(1, slotB)

    float acc0, acc1, acc2, acc3;

    asm volatile("s_waitcnt vmcnt(%0)" :: "n"(NJ) : "memory");   // ch0 done
    COMPUTE(acc0, slot)
    // guarantee ch0's LDS reads retired before DMA overwrites slot A
    asm volatile("s_waitcnt lgkmcnt(0)" ::: "memory");
    __builtin_amdgcn_sched_barrier(0);
    ISSUE(2, slot)

    asm volatile("s_waitcnt vmcnt(%0)" :: "n"(NJ) : "memory");   // ch1 done
    COMPUTE(acc1, slotB)
    asm volatile("s_waitcnt lgkmcnt(0)" ::: "memory");
    __builtin_amdgcn_sched_barrier(0);
    ISSUE(3, slotB)

    asm volatile("s_waitcnt vmcnt(%0)" :: "n"(NJ) : "memory");   // ch2 done
    COMPUTE(acc2, slot)

    asm volatile("s_waitcnt vmcnt(0)" ::: "memory");             // ch3 done
    COMPUTE(acc3, slotB)

#undef ISSUE
#undef COMPUTE

    if (lane < POOL * POOL) {
        float* ob = out + ((size_t)(r * CCH + c0)) * (POOL * POOL) + bin;
        ob[0 * POOL * POOL] = acc0 * 0.25f;
        ob[1 * POOL * POOL] = acc1 * 0.25f;
        ob[2 * POOL * POOL] = acc2 * 0.25f;
        ob[3 * POOL * POOL] = acc3 * 0.25f;
    }
}

// Single fused kernel: one block = 4 waves x 4 channels = 16 ch of one ROI.
__global__ __launch_bounds__(NT) void roi_main(
    const float* __restrict__ x, const float* __restrict__ rois,
    float* __restrict__ out)
{
    __shared__ float tile[(NT / 64) * 2 * SLOTF];   // 28672 B

    const int bid  = blockIdx.x;
    const int r    = bid >> 4;                 // 16 groups per ROI
    const int g    = bid & 15;
    const int wid  = threadIdx.x >> 6;
    const int lane = threadIdx.x & 63;
    const int c0   = g * (ITEMS * NT / 64) + wid * ITEMS;

    // ---- per-ROI params (L2-hot broadcast reads) ----
    const float r0  = rois[r * 5 + 0];
    const float sx0 = rois[r * 5 + 1] * SCALE - 0.5f;
    const float sy0 = rois[r * 5 + 2] * SCALE - 0.5f;
    const float bw  = (rois[r * 5 + 3] * SCALE - 0.5f - sx0) * (1.0f / POOL);
    const float bh  = (rois[r * 5 + 4] * SCALE - 0.5f - sy0) * (1.0f / POOL);
    const int   n   = (int)r0;

    // ---- this lane's raw taps (x pair folded for pair-reads, y standard) --
    const int bin = (lane < POOL * POOL) ? lane : POOL * POOL - 1;
    const int py  = bin / POOL;
    const int px  = bin - py * POOL;

    int xlo0r, xlo1r; float wx10, wx20, wx11, wx21;
    {
        int lo, hi; float w1, w2;
        tap_calc(sx0, bw, px * 2,     WW, lo, hi, w1, w2);
        if (hi == lo) { w1 += w2; w2 = 0.0f; }
        xlo0r = lo; wx10 = w1; wx20 = w2;
        tap_calc(sx0, bw, px * 2 + 1, WW, lo, hi, w1, w2);
        if (hi == lo) { w1 += w2; w2 = 0.0f; }
        xlo1r = lo; wx11 = w1; wx21 = w2;
    }
    int ylo0r, yhi0r, ylo1r, yhi1r; float wy10, wy20, wy11, wy21;
    tap_calc(sy0, bh, py * 2,     HH, ylo0r, yhi0r, wy10, wy20);
    tap_calc(sy0, bh, py * 2 + 1, HH, ylo1r, yhi1r, wy11, wy21);

    // ---- bbox via readlane (taps monotonic: lane 0 = min, lane 48 = max) --
    const int xmin_al = __builtin_amdgcn_readlane(xlo0r, 0) & ~3;
    const int ymin    = __builtin_amdgcn_readlane(ylo0r, 0);
    const int xmaxr   = __builtin_amdgcn_readlane(xlo1r, 48);
    const int ymaxr   = __builtin_amdgcn_readlane(yhi1r, 48);
    int TH  = ymaxr - ymin + 1;             if (TH > MAXTH) TH = MAXTH;
    int nb4 = ((min(xmaxr + 1, WW - 1) - xmin_al) >> 2) + 1;
    if (nb4 > 8) nb4 = 8;
    const int magic = (int)ceilf(65536.0f / (float)nb4);
    const int tot   = TH * nb4;
    const int TWp   = nb4 << 2;
    const int nj    = (tot + 63) >> 6;      // 1..4

    // ---- 8 pair-bases + 16 weights (shared by all 4 channels) ----
    int   off[8];
    float wgt[16];
    {
        const int xlo0 = max(xlo0r - xmin_al, 0);
        const int xlo1 = max(xlo1r - xmin_al, 0);
        const int rl0  = max(ylo0r - ymin, 0) * TWp;
        const int rh0  = max(yhi0r - ymin, 0) * TWp;
        const int rl1  = max(ylo1r - ymin, 0) * TWp;
        const int rh1  = max(yhi1r - ymin, 0) * TWp;
        off[0] = rl0 + xlo0;  wgt[0]  = wy10 * wx10;  wgt[1]  = wy10 * wx20;
        off[1] = rl0 + xlo1;  wgt[2]  = wy10 * wx11;  wgt[3]  = wy10 * wx21;
        off[2] = rh0 + xlo0;  wgt[4]  = wy20 * wx10;  wgt[5]  = wy20 * wx20;
        off[3] = rh0 + xlo1;  wgt[6]  = wy20 * wx11;  wgt[7]  = wy20 * wx21;
        off[4] = rl1 + xlo0;  wgt[8]  = wy11 * wx10;  wgt[9]  = wy11 * wx20;
        off[5] = rl1 + xlo1;  wgt[10] = wy11 * wx11;  wgt[11] = wy11 * wx21;
        off[6] = rh1 + xlo0;  wgt[12] = wy21 * wx10;  wgt[13] = wy21 * wx20;
        off[7] = rh1 + xlo1;  wgt[14] = wy21 * wx11;  wgt[15] = wy21 * wx21;
    }

    float* slot = tile + wid * (2 * SLOTF);

    switch (nj) {
    case 1:  run4<1>(x, out, slot, n, c0, r, xmin_al, ymin, TWp, tot, magic, nb4, lane, off, wgt, bin); break;
    case 2:  run4<2>(x, out, slot, n, c0, r, xmin_al, ymin, TWp, tot, magic, nb4, lane, off, wgt, bin); break;
    case 3:  run4<3>(x, out, slot, n, c0, r, xmin_al, ymin, TWp, tot, magic, nb4, lane, off, wgt, bin); break;
    default: run4<4>(x, out, slot, n, c0, r, xmin_al, ymin, TWp, tot, magic, nb4, lane, off, wgt, bin); break;
    }
}

extern "C" void kernel_launch(void* const* d_in, const int* in_sizes, int n_in,
                              void* d_out, int out_size, void* d_ws, size_t ws_size,
                              hipStream_t stream) {
    const float* x    = (const float*)d_in[0];
    const float* rois = (const float*)d_in[1];
    float*       out  = (float*)d_out;

    const int R = in_sizes[1] / 5;
    roi_main<<<R * 16, NT, 0, stream>>>(x, rois, out);
}